// Round 9
// baseline (261.982 us; speedup 1.0000x reference)
//
#include <hip/hip_runtime.h>
#include <math.h>

#define C_DIM 512
#define T_DIM 2048
#define B_DIM 8

typedef _Float16 f16;
typedef __attribute__((ext_vector_type(8))) _Float16 half8;
typedef __attribute__((ext_vector_type(4))) _Float16 half4;
typedef __attribute__((ext_vector_type(4))) float floatx4;

// ---------------------------------------------------------------------------
// Merged prep kernel (R8): one launch does all three independent prep jobs.
// ---------------------------------------------------------------------------
__global__ __launch_bounds__(256) void prep_kernel(
    const float* __restrict__ x, f16* __restrict__ xt,
    const float* __restrict__ w0, const float* __restrict__ w1,
    const float* __restrict__ w2, const float* __restrict__ w3,
    f16* __restrict__ o0, f16* __restrict__ o1,
    f16* __restrict__ o2, f16* __restrict__ o3,
    const float* __restrict__ b0, const float* __restrict__ b1,
    float* __restrict__ ob)
{
    __shared__ float xs[32][33];
    const int blk = blockIdx.x;
    const int tid = threadIdx.x;

    if (blk < 1024) {
        const float* src; f16* dst;
        switch (blk >> 8) {
            case 0:  src = w0; dst = o0; break;
            case 1:  src = w1; dst = o1; break;
            case 2:  src = w2; dst = o2; break;
            default: src = w3; dst = o3; break;
        }
        const int idx = ((blk & 255) * 256 + tid) * 4;
        const float4 v = *(const float4*)(src + idx);
        half4 h; h[0] = (f16)v.x; h[1] = (f16)v.y; h[2] = (f16)v.z; h[3] = (f16)v.w;
        *(half4*)(dst + idx) = h;
        return;
    }
    if (blk < 1028) {
        const int i = (blk - 1024) * 256 + tid;
        ob[i] = (i < 512) ? b0[i] : b1[i - 512];
        return;
    }
    {
        const int rr = blk - 1028;
        const int b  = rr >> 10;
        const int rem = rr & 1023;
        const int t0 = (rem & 63) * 32;
        const int c0 = (rem >> 6) * 32;
        const float* xb = x + (size_t)b * C_DIM * T_DIM;
        const int r = tid >> 3, q = tid & 7;

        const float4 v = *(const float4*)(xb + (size_t)(c0 + r) * T_DIM + t0 + q * 4);
        xs[r][q * 4 + 0] = v.x; xs[r][q * 4 + 1] = v.y;
        xs[r][q * 4 + 2] = v.z; xs[r][q * 4 + 3] = v.w;
        __syncthreads();

        f16* xtb = xt + (size_t)b * C_DIM * T_DIM;
        half4 h;
        h[0] = (f16)xs[q * 4 + 0][r]; h[1] = (f16)xs[q * 4 + 1][r];
        h[2] = (f16)xs[q * 4 + 2][r]; h[3] = (f16)xs[q * 4 + 3][r];
        *(half4*)(xtb + (size_t)(t0 + r) * C_DIM + c0 + q * 4) = h;
    }
}

// ---------------------------------------------------------------------------
// global_load_lds: 16B/lane, LDS dest = wave-uniform base + lane*16 (linear).
// ---------------------------------------------------------------------------
__device__ __forceinline__ void gl16(const f16* g, f16* l)
{
    __builtin_amdgcn_global_load_lds(
        (const __attribute__((address_space(1))) unsigned int*)g,
        (__attribute__((address_space(3))) unsigned int*)l,
        16, 0, 0);
}

// ---------------------------------------------------------------------------
// LDS chunk swizzle (R6, verified 0 conflicts): logical chunk q of row r is
// stored at physical chunk q ^ ((r>>1)&3). Reads XOR (l16>>1)&3; gl16
// pre-swizzles the GLOBAL source chunk with (lane>>3)&3 (staged row=lane>>2).
// ---------------------------------------------------------------------------

// ---------------------------------------------------------------------------
// 256x256 TN MFMA GEMM (R6/R8 state). MODE: 0 = f16 store; 1 = relu+bias[col].
// ---------------------------------------------------------------------------
template<int MODE>
__global__ __launch_bounds__(512, 2) void gemm256(
    const f16* __restrict__ A, size_t sA, int lda,
    const f16* __restrict__ B, size_t sB, int ldb,
    void* __restrict__ Cp, size_t sC, int ldc,
    const float* __restrict__ bias,
    int gx, int K)
{
    __shared__ __align__(16) f16 As[2][2][256 * 32];   // 64 KB
    __shared__ __align__(16) f16 Bs[2][2][256 * 32];   // 64 KB

    const int f = blockIdx.x;
    const int bz = f & 7;
    const int flat = f >> 3;
    const int jsc = gx >> 2;
    const int sh = (jsc <= 1) ? 0 : (31 - __builtin_clz(jsc));
    const int s = flat >> 4, rem = flat & 15;
    const int i0 = ((s >> sh) * 4 + (rem >> 2)) * 256;
    const int j0 = (((jsc <= 1) ? 0 : (s & (jsc - 1))) * 4 + (rem & 3)) * 256;

    A += (size_t)bz * sA;
    B += (size_t)bz * sB;

    const int tid  = threadIdx.x;
    const int lane = tid & 63;
    const int wave = tid >> 6;
    const int wy = wave >> 2;
    const int wx = wave & 3;
    const int quad = lane >> 4, l16 = lane & 15;

    const int srow = wave * 32 + (lane >> 2);
    const int sch  = (lane & 3) ^ ((lane >> 3) & 3);
    const f16* gA0 = A + (size_t)(i0 + srow) * lda + sch * 8;
    const f16* gA1 = gA0 + (size_t)16 * lda;
    const f16* gB0 = B + (size_t)(j0 + srow) * ldb + sch * 8;
    const f16* gB1 = gB0 + (size_t)16 * ldb;
    const int wsg = wave * 1024;

    const int xq = (quad ^ ((l16 >> 1) & 3)) << 3;
    const int ra = (wy * 128 + l16) * 32 + xq;
    const int rb = (wx * 64 + l16) * 32 + xq;

    const int nt = K >> 6;

#define STAGE_A(t, q) do {                                                    \
        const int off_ = (t) * 64 + (q) * 32;                                 \
        gl16(gA0 + off_, &As[(t) & 1][q][wsg]);                               \
        gl16(gA1 + off_, &As[(t) & 1][q][wsg + 512]);                         \
    } while (0)
#define STAGE_B(t, q) do {                                                    \
        const int off_ = (t) * 64 + (q) * 32;                                 \
        gl16(gB0 + off_, &Bs[(t) & 1][q][wsg]);                               \
        gl16(gB1 + off_, &Bs[(t) & 1][q][wsg + 512]);                         \
    } while (0)
#define PH_MFMA(B0) do {                                                      \
        __builtin_amdgcn_s_setprio(1);                                        \
        _Pragma("unroll")                                                     \
        for (int mi = 0; mi < 4; ++mi) {                                      \
            _Pragma("unroll")                                                 \
            for (int ni = 0; ni < 4; ++ni)                                    \
                acc[(B0) + mi][ni] = __builtin_amdgcn_mfma_f32_16x16x32_f16(  \
                    af[mi], bf[ni], acc[(B0) + mi][ni], 0, 0, 0);             \
        }                                                                     \
        __builtin_amdgcn_s_setprio(0);                                        \
    } while (0)

    STAGE_A(0, 0); STAGE_B(0, 0);
    STAGE_A(0, 1); STAGE_B(0, 1);
    STAGE_A(1, 0); STAGE_B(1, 0);

    floatx4 acc[8][4] = {};

    for (int t = 0; t < nt; ++t) {
        const f16* sa0 = &As[t & 1][0][0];
        const f16* sb0 = &Bs[t & 1][0][0];
        const f16* sa1 = &As[t & 1][1][0];
        const f16* sb1 = &Bs[t & 1][1][0];
        half8 af[4], bf[4];

        if (t + 1 < nt) asm volatile("s_waitcnt vmcnt(8)\ns_barrier" ::: "memory");
        else            asm volatile("s_waitcnt vmcnt(4)\ns_barrier" ::: "memory");
        #pragma unroll
        for (int ni = 0; ni < 4; ++ni) bf[ni] = *(const half8*)&sb0[rb + ni * 512];
        #pragma unroll
        for (int mi = 0; mi < 4; ++mi) af[mi] = *(const half8*)&sa0[ra + mi * 512];
        if (t + 1 < nt) STAGE_A(t + 1, 1);
        PH_MFMA(0);

        #pragma unroll
        for (int mi = 0; mi < 4; ++mi) af[mi] = *(const half8*)&sa0[ra + 2048 + mi * 512];
        if (t + 1 < nt) STAGE_B(t + 1, 1);
        PH_MFMA(4);

        if (t + 1 < nt) asm volatile("s_waitcnt vmcnt(8)\ns_barrier" ::: "memory");
        else            asm volatile("s_waitcnt vmcnt(0)\ns_barrier" ::: "memory");
        #pragma unroll
        for (int ni = 0; ni < 4; ++ni) bf[ni] = *(const half8*)&sb1[rb + ni * 512];
        #pragma unroll
        for (int mi = 0; mi < 4; ++mi) af[mi] = *(const half8*)&sa1[ra + mi * 512];
        if (t + 2 < nt) STAGE_A(t + 2, 0);
        PH_MFMA(0);

        #pragma unroll
        for (int mi = 0; mi < 4; ++mi) af[mi] = *(const half8*)&sa1[ra + 2048 + mi * 512];
        if (t + 2 < nt) STAGE_B(t + 2, 0);
        PH_MFMA(4);
    }
#undef STAGE_A
#undef STAGE_B
#undef PH_MFMA

    #pragma unroll
    for (int m = 0; m < 8; ++m) {
        #pragma unroll
        for (int ni = 0; ni < 4; ++ni) {
            const int col = j0 + wx * 64 + ni * 16 + l16;
            #pragma unroll
            for (int r = 0; r < 4; ++r) {
                const int row = i0 + wy * 128 + m * 16 + quad * 4 + r;
                float v = acc[m][ni][r];
                if (MODE == 1) { v += bias[col]; v = v > 0.f ? v : 0.f; }
                ((f16*)Cp)[(size_t)bz * sC + (size_t)row * ldc + col] = (f16)v;
            }
        }
    }
}

// ---------------------------------------------------------------------------
// R9: seamless dual-tile 256x256 TN GEMM for the scores GEMM (K=512, nt=8).
// Each block computes TWO output tiles (j, j+256) sharing the A panel, as one
// 16-virtual-tile K-loop: B addr adds (t>>3)*256*ldb, A offsets wrap (t&7),
// LDS ring parity and the counted-vmcnt(8) ledger run straight through the
// boundary. At t==nt8 (after the ph0 barrier) the accumulator is dumped to C
// and re-zeroed (stores transiently inflate vmcnt -> one bounded over-wait).
// Grid = 32 inner x 8 batches = 256 blocks = 1/CU, single round: one
// fill+drain instead of two, A re-fetch halved.
// ---------------------------------------------------------------------------
__global__ __launch_bounds__(512, 2) void gemm256_dual(
    const f16* __restrict__ A, size_t sA, int lda,
    const f16* __restrict__ B, size_t sB, int ldb,
    f16* __restrict__ Cp, size_t sC, int ldc,
    int K)
{
    __shared__ __align__(16) f16 As[2][2][256 * 32];   // 64 KB
    __shared__ __align__(16) f16 Bs[2][2][256 * 32];   // 64 KB

    const int f = blockIdx.x;
    const int bz = f & 7;               // batch->XCD pinning
    const int inner = f >> 3;           // 0..31
    const int i0 = (inner >> 2) * 256;  // 8 i-tiles
    const int jb = (inner & 3) * 512;   // 4 j-pairs

    A += (size_t)bz * sA;
    B += (size_t)bz * sB;

    const int tid  = threadIdx.x;
    const int lane = tid & 63;
    const int wave = tid >> 6;
    const int wy = wave >> 2;
    const int wx = wave & 3;
    const int quad = lane >> 4, l16 = lane & 15;

    const int srow = wave * 32 + (lane >> 2);
    const int sch  = (lane & 3) ^ ((lane >> 3) & 3);
    const f16* gA0 = A + (size_t)(i0 + srow) * lda + sch * 8;
    const f16* gA1 = gA0 + (size_t)16 * lda;
    const f16* gB0 = B + (size_t)(jb + srow) * ldb + sch * 8;
    const f16* gB1 = gB0 + (size_t)16 * ldb;
    const int wsg = wave * 1024;

    const int xq = (quad ^ ((l16 >> 1) & 3)) << 3;
    const int ra = (wy * 128 + l16) * 32 + xq;
    const int rb = (wx * 64 + l16) * 32 + xq;

    const int nt8 = K >> 6;        // 8
    const int ntv = nt8 * 2;       // 16 virtual tiles

#define DSTAGE_A(t, q) do {                                                   \
        const int off_ = ((t) & 7) * 64 + (q) * 32;                           \
        gl16(gA0 + off_, &As[(t) & 1][q][wsg]);                               \
        gl16(gA1 + off_, &As[(t) & 1][q][wsg + 512]);                         \
    } while (0)
#define DSTAGE_B(t, q) do {                                                   \
        const size_t off_ = (size_t)((t) >> 3) * 256 * ldb                    \
                          + ((t) & 7) * 64 + (q) * 32;                        \
        gl16(gB0 + off_, &Bs[(t) & 1][q][wsg]);                               \
        gl16(gB1 + off_, &Bs[(t) & 1][q][wsg + 512]);                         \
    } while (0)
#define PH_MFMA(B0) do {                                                      \
        __builtin_amdgcn_s_setprio(1);                                        \
        _Pragma("unroll")                                                     \
        for (int mi = 0; mi < 4; ++mi) {                                      \
            _Pragma("unroll")                                                 \
            for (int ni = 0; ni < 4; ++ni)                                    \
                acc[(B0) + mi][ni] = __builtin_amdgcn_mfma_f32_16x16x32_f16(  \
                    af[mi], bf[ni], acc[(B0) + mi][ni], 0, 0, 0);             \
        }                                                                     \
        __builtin_amdgcn_s_setprio(0);                                        \
    } while (0)
#define DUMP(J0) do {                                                         \
        _Pragma("unroll")                                                     \
        for (int m = 0; m < 8; ++m) {                                         \
            _Pragma("unroll")                                                 \
            for (int ni = 0; ni < 4; ++ni) {                                  \
                const int col = (J0) + wx * 64 + ni * 16 + l16;               \
                _Pragma("unroll")                                             \
                for (int r = 0; r < 4; ++r) {                                 \
                    const int row = i0 + wy * 128 + m * 16 + quad * 4 + r;    \
                    Cp[(size_t)bz * sC + (size_t)row * ldc + col] =           \
                        (f16)acc[m][ni][r];                                   \
                    acc[m][ni][r] = 0.f;                                      \
                }                                                             \
            }                                                                 \
        }                                                                     \
    } while (0)

    DSTAGE_A(0, 0); DSTAGE_B(0, 0);
    DSTAGE_A(0, 1); DSTAGE_B(0, 1);
    DSTAGE_A(1, 0); DSTAGE_B(1, 0);

    floatx4 acc[8][4] = {};

    for (int t = 0; t < ntv; ++t) {
        const f16* sa0 = &As[t & 1][0][0];
        const f16* sb0 = &Bs[t & 1][0][0];
        const f16* sa1 = &As[t & 1][1][0];
        const f16* sb1 = &Bs[t & 1][1][0];
        half8 af[4], bf[4];

        if (t + 1 < ntv) asm volatile("s_waitcnt vmcnt(8)\ns_barrier" ::: "memory");
        else             asm volatile("s_waitcnt vmcnt(4)\ns_barrier" ::: "memory");
        if (t == nt8) DUMP(jb);   // tile-0 output; overlaps next staging
        #pragma unroll
        for (int ni = 0; ni < 4; ++ni) bf[ni] = *(const half8*)&sb0[rb + ni * 512];
        #pragma unroll
        for (int mi = 0; mi < 4; ++mi) af[mi] = *(const half8*)&sa0[ra + mi * 512];
        if (t + 1 < ntv) DSTAGE_A(t + 1, 1);
        PH_MFMA(0);

        #pragma unroll
        for (int mi = 0; mi < 4; ++mi) af[mi] = *(const half8*)&sa0[ra + 2048 + mi * 512];
        if (t + 1 < ntv) DSTAGE_B(t + 1, 1);
        PH_MFMA(4);

        if (t + 1 < ntv) asm volatile("s_waitcnt vmcnt(8)\ns_barrier" ::: "memory");
        else             asm volatile("s_waitcnt vmcnt(0)\ns_barrier" ::: "memory");
        #pragma unroll
        for (int ni = 0; ni < 4; ++ni) bf[ni] = *(const half8*)&sb1[rb + ni * 512];
        #pragma unroll
        for (int mi = 0; mi < 4; ++mi) af[mi] = *(const half8*)&sa1[ra + mi * 512];
        if (t + 2 < ntv) DSTAGE_A(t + 2, 0);
        PH_MFMA(0);

        #pragma unroll
        for (int mi = 0; mi < 4; ++mi) af[mi] = *(const half8*)&sa1[ra + 2048 + mi * 512];
        if (t + 2 < ntv) DSTAGE_B(t + 2, 0);
        PH_MFMA(4);
    }

    DUMP(jb + 256);   // tile-1 output
#undef DSTAGE_A
#undef DSTAGE_B
#undef PH_MFMA
#undef DUMP
}

// ---------------------------------------------------------------------------
// 128(M)x256(N) TN MFMA GEMM (R6/R8 state). gxn = N-tiles per row.
// MODE: 0 = f16 store; 2 = f16 relu(+bias[row]); 3 = fp32 relu(+bias[row])+resid.
// ---------------------------------------------------------------------------
template<int MODE>
__global__ __launch_bounds__(512, 2) void gemm_wide(
    const f16* __restrict__ A, size_t sA, int lda,
    const f16* __restrict__ B, size_t sB, int ldb,
    void* __restrict__ Cp, size_t sC, int ldc,
    const float* __restrict__ bias,
    const float* __restrict__ resid, size_t sR,
    int gxn, int K)
{
    __shared__ __align__(16) f16 As[2][2][128 * 32];   // 32 KB
    __shared__ __align__(16) f16 Bs[2][2][256 * 32];   // 64 KB

    const int f = blockIdx.x;
    const int bz = f & 7;
    const int inner = f >> 3;
    const int j0 = (inner % gxn) * 256;
    const int i0 = (inner / gxn) * 128;
    A += (size_t)bz * sA;
    B += (size_t)bz * sB;

    const int tid  = threadIdx.x;
    const int lane = tid & 63;
    const int wave = tid >> 6;
    const int wy = wave >> 2;
    const int wx = wave & 3;
    const int quad = lane >> 4, l16 = lane & 15;

    const int sch = (lane & 3) ^ ((lane >> 3) & 3);
    const f16* gA0 = A + (size_t)(i0 + wave * 16 + (lane >> 2)) * lda + sch * 8;
    const f16* gB0 = B + (size_t)(j0 + wave * 32 + (lane >> 2)) * ldb + sch * 8;
    const f16* gB1 = gB0 + (size_t)16 * ldb;

    const int xq = (quad ^ ((l16 >> 1) & 3)) << 3;
    const int ra = (wy * 64 + l16) * 32 + xq;
    const int rb = (wx * 64 + l16) * 32 + xq;

    const int nt = K >> 6;

#define WSTAGE_A(t, q) do {                                                   \
        gl16(gA0 + (t) * 64 + (q) * 32, &As[(t) & 1][q][wave * 512]);         \
    } while (0)
#define WSTAGE_B(t, q) do {                                                   \
        const int off_ = (t) * 64 + (q) * 32;                                 \
        gl16(gB0 + off_, &Bs[(t) & 1][q][wave * 1024]);                       \
        gl16(gB1 + off_, &Bs[(t) & 1][q][wave * 1024 + 512]);                 \
    } while (0)
#define WPH_MFMA() do {                                                       \
        __builtin_amdgcn_s_setprio(1);                                        \
        _Pragma("unroll")                                                     \
        for (int mi = 0; mi < 4; ++mi) {                                      \
            _Pragma("unroll")                                                 \
            for (int ni = 0; ni < 4; ++ni)                                    \
                acc[mi][ni] = __builtin_amdgcn_mfma_f32_16x16x32_f16(         \
                    af[mi], bf[ni], acc[mi][ni], 0, 0, 0);                    \
        }                                                                     \
        __builtin_amdgcn_s_setprio(0);                                        \
    } while (0)

    WSTAGE_A(0, 0); WSTAGE_B(0, 0);
    WSTAGE_A(0, 1); WSTAGE_B(0, 1);
    WSTAGE_A(1, 0); WSTAGE_B(1, 0);

    floatx4 acc[4][4] = {};

    for (int t = 0; t < nt; ++t) {
        const f16* sa0 = &As[t & 1][0][0];
        const f16* sb0 = &Bs[t & 1][0][0];
        const f16* sa1 = &As[t & 1][1][0];
        const f16* sb1 = &Bs[t & 1][1][0];
        half8 af[4], bf[4];

        if (t + 1 < nt) asm volatile("s_waitcnt vmcnt(6)\ns_barrier" ::: "memory");
        else            asm volatile("s_waitcnt vmcnt(3)\ns_barrier" ::: "memory");
        #pragma unroll
        for (int ni = 0; ni < 4; ++ni) bf[ni] = *(const half8*)&sb0[rb + ni * 512];
        #pragma unroll
        for (int mi = 0; mi < 4; ++mi) af[mi] = *(const half8*)&sa0[ra + mi * 512];
        if (t + 1 < nt) { WSTAGE_A(t + 1, 1); WSTAGE_B(t + 1, 1); }
        WPH_MFMA();

        if (t + 1 < nt) asm volatile("s_waitcnt vmcnt(6)\ns_barrier" ::: "memory");
        else            asm volatile("s_waitcnt vmcnt(0)\ns_barrier" ::: "memory");
        #pragma unroll
        for (int ni = 0; ni < 4; ++ni) bf[ni] = *(const half8*)&sb1[rb + ni * 512];
        #pragma unroll
        for (int mi = 0; mi < 4; ++mi) af[mi] = *(const half8*)&sa1[ra + mi * 512];
        if (t + 2 < nt) { WSTAGE_A(t + 2, 0); WSTAGE_B(t + 2, 0); }
        WPH_MFMA();
    }
#undef WSTAGE_A
#undef WSTAGE_B
#undef WPH_MFMA

    #pragma unroll
    for (int mi = 0; mi < 4; ++mi) {
        #pragma unroll
        for (int ni = 0; ni < 4; ++ni) {
            const int col = j0 + wx * 64 + ni * 16 + l16;
            #pragma unroll
            for (int r = 0; r < 4; ++r) {
                const int row = i0 + wy * 64 + mi * 16 + quad * 4 + r;
                float v = acc[mi][ni][r];
                if (MODE == 2) { v += bias[row]; v = v > 0.f ? v : 0.f; }
                if (MODE == 3) {
                    v += bias[row];
                    v = v > 0.f ? v : 0.f;
                    v += resid[(size_t)bz * sR + (size_t)row * ldc + col];
                    ((float*)Cp)[(size_t)bz * sC + (size_t)row * ldc + col] = v;
                } else {
                    ((f16*)Cp)[(size_t)bz * sC + (size_t)row * ldc + col] = (f16)v;
                }
            }
        }
    }
}

// ---------------------------------------------------------------------------
// in-place fp16 softmax over rows of 2048 (fp32 math). One wave per row,
// 4 rows/block, butterfly shfl_xor reductions — no barriers, no LDS.
// ---------------------------------------------------------------------------
__global__ __launch_bounds__(256) void softmax_f16_kernel(f16* __restrict__ S)
{
    const int lane = threadIdx.x & 63;
    f16* p = S + (size_t)(blockIdx.x * 4 + (threadIdx.x >> 6)) * T_DIM;

    half8 h[4];
    float v[32];
    float m = -1e30f;
    #pragma unroll
    for (int u = 0; u < 4; ++u) {
        h[u] = *((const half8*)p + (u * 64 + lane));
        #pragma unroll
        for (int c = 0; c < 8; ++c) {
            v[u * 8 + c] = (float)h[u][c];
            m = fmaxf(m, v[u * 8 + c]);
        }
    }
    #pragma unroll
    for (int off = 32; off; off >>= 1) m = fmaxf(m, __shfl_xor(m, off));

    float s = 0.f;
    #pragma unroll
    for (int i = 0; i < 32; ++i) { v[i] = __expf(v[i] - m); s += v[i]; }
    #pragma unroll
    for (int off = 32; off; off >>= 1) s += __shfl_xor(s, off);
    const float inv = 1.f / s;

    #pragma unroll
    for (int u = 0; u < 4; ++u) {
        #pragma unroll
        for (int c = 0; c < 8; ++c) h[u][c] = (f16)(v[u * 8 + c] * inv);
        *((half8*)p + (u * 64 + lane)) = h[u];
    }
}

// ---------------------------------------------------------------------------
extern "C" void kernel_launch(void* const* d_in, const int* in_sizes, int n_in,
                              void* d_out, int out_size, void* d_ws, size_t ws_size,
                              hipStream_t stream)
{
    const float* x       = (const float*)d_in[0];
    const float* w_theta = (const float*)d_in[1];
    const float* b_theta = (const float*)d_in[2];
    const float* w_phi   = (const float*)d_in[3];
    const float* b_phi   = (const float*)d_in[4];
    const float* w_g     = (const float*)d_in[5];
    const float* b_g     = (const float*)d_in[6];
    const float* w_w     = (const float*)d_in[7];
    const float* b_w     = (const float*)d_in[8];
    float* out = (float*)d_out;

    const size_t FE = (size_t)B_DIM * C_DIM * T_DIM;   // 8.4M
    const size_t TC = (size_t)T_DIM * C_DIM;
    const size_t TT = (size_t)T_DIM * T_DIM;

    f16* xt      = (f16*)d_ws;
    f16* wtp     = xt + FE;              // merged theta|phi weights [1024][512]
    f16* wg_h    = wtp + 524288;
    f16* ww_h    = wg_h + 262144;
    float* btp   = (float*)(ww_h + 262144);   // merged bias [1024] fp32
    f16* tp      = (f16*)(btp + 1024);   // theta|phi acts [B][T][1024]
    f16* g       = tp + (size_t)B_DIM * T_DIM * 1024;
    f16* scores  = g + FE;               // B*T*T fp16 = 67 MB
    f16* feature = tp;                   // tp dead after scores GEMM

    const dim3 blk(256);
    const dim3 blk512(512);

    // merged prep: weight convert + bias concat + x transpose (one launch)
    prep_kernel<<<dim3(1024 + 4 + 8192), blk, 0, stream>>>(
        x, xt, w_theta, w_phi, w_g, w_w,
        wtp, wtp + 262144, wg_h, ww_h, b_theta, b_phi, btp);

    // merged theta|phi conv: tp[t][0:1024] = relu(xt . wtp + btp)  M=T,N=1024
    gemm256<1><<<dim3(4 * 8 * B_DIM), blk512, 0, stream>>>(
        xt, TC, C_DIM, wtp, 0, C_DIM, tp, (size_t)T_DIM * 1024, 1024,
        btp, 4, C_DIM);
    // g[c][t] = relu(w_g . xt + b_g[c])   M=C=512, N=T
    gemm_wide<2><<<dim3(8 * 4 * B_DIM), blk512, 0, stream>>>(
        wg_h, 0, C_DIM, xt, TC, C_DIM, g, TC, T_DIM, b_g, nullptr, 0,
        8, C_DIM);
    // scores[i][j] = theta . phi — dual-tile seamless, 256 blocks = 1 round
    gemm256_dual<<<dim3(256), blk512, 0, stream>>>(
        tp, (size_t)T_DIM * 1024, 1024, tp + 512, (size_t)T_DIM * 1024, 1024,
        scores, TT, T_DIM, C_DIM);
    softmax_f16_kernel<<<dim3(B_DIM * T_DIM / 4), blk, 0, stream>>>(scores);
    // feature[i][c] = attn . g   M=T, N=C=512, K=T
    gemm_wide<0><<<dim3(2 * 16 * B_DIM), blk512, 0, stream>>>(
        scores, TT, T_DIM, g, TC, T_DIM, feature, TC, C_DIM,
        nullptr, nullptr, 0, 2, T_DIM);
    // out[c][t] = relu(w_w . feature + b_w[c]) + x   M=C=512, N=T
    gemm_wide<3><<<dim3(8 * 4 * B_DIM), blk512, 0, stream>>>(
        ww_h, 0, C_DIM, feature, TC, C_DIM, out, TC, T_DIM, b_w, x, TC,
        8, C_DIM);
}

// Round 10
// 248.962 us; speedup vs baseline: 1.0523x; 1.0523x over previous
//
#include <hip/hip_runtime.h>
#include <math.h>

#define C_DIM 512
#define T_DIM 2048
#define B_DIM 8

typedef _Float16 f16;
typedef __attribute__((ext_vector_type(8))) _Float16 half8;
typedef __attribute__((ext_vector_type(4))) _Float16 half4;
typedef __attribute__((ext_vector_type(4))) float floatx4;

// ---------------------------------------------------------------------------
// Merged prep kernel (R8): one launch does all three independent prep jobs.
//   blocks [0, 1024)      : fp32->fp16 weight convert (4 matrices x 256 blks)
//   blocks [1024, 1028)   : bias concat (1024 threads)
//   blocks [1028, 9220)   : x [B][C][T] fp32 -> xt [B][T][C] f16 transpose
// ---------------------------------------------------------------------------
__global__ __launch_bounds__(256) void prep_kernel(
    const float* __restrict__ x, f16* __restrict__ xt,
    const float* __restrict__ w0, const float* __restrict__ w1,
    const float* __restrict__ w2, const float* __restrict__ w3,
    f16* __restrict__ o0, f16* __restrict__ o1,
    f16* __restrict__ o2, f16* __restrict__ o3,
    const float* __restrict__ b0, const float* __restrict__ b1,
    float* __restrict__ ob)
{
    __shared__ float xs[32][33];
    const int blk = blockIdx.x;
    const int tid = threadIdx.x;

    if (blk < 1024) {
        const float* src; f16* dst;
        switch (blk >> 8) {
            case 0:  src = w0; dst = o0; break;
            case 1:  src = w1; dst = o1; break;
            case 2:  src = w2; dst = o2; break;
            default: src = w3; dst = o3; break;
        }
        const int idx = ((blk & 255) * 256 + tid) * 4;
        const float4 v = *(const float4*)(src + idx);
        half4 h; h[0] = (f16)v.x; h[1] = (f16)v.y; h[2] = (f16)v.z; h[3] = (f16)v.w;
        *(half4*)(dst + idx) = h;
        return;
    }
    if (blk < 1028) {
        const int i = (blk - 1024) * 256 + tid;
        ob[i] = (i < 512) ? b0[i] : b1[i - 512];
        return;
    }
    {
        const int rr = blk - 1028;
        const int b  = rr >> 10;
        const int rem = rr & 1023;
        const int t0 = (rem & 63) * 32;
        const int c0 = (rem >> 6) * 32;
        const float* xb = x + (size_t)b * C_DIM * T_DIM;
        const int r = tid >> 3, q = tid & 7;

        const float4 v = *(const float4*)(xb + (size_t)(c0 + r) * T_DIM + t0 + q * 4);
        xs[r][q * 4 + 0] = v.x; xs[r][q * 4 + 1] = v.y;
        xs[r][q * 4 + 2] = v.z; xs[r][q * 4 + 3] = v.w;
        __syncthreads();

        f16* xtb = xt + (size_t)b * C_DIM * T_DIM;
        half4 h;
        h[0] = (f16)xs[q * 4 + 0][r]; h[1] = (f16)xs[q * 4 + 1][r];
        h[2] = (f16)xs[q * 4 + 2][r]; h[3] = (f16)xs[q * 4 + 3][r];
        *(half4*)(xtb + (size_t)(t0 + r) * C_DIM + c0 + q * 4) = h;
    }
}

// ---------------------------------------------------------------------------
// global_load_lds: 16B/lane, LDS dest = wave-uniform base + lane*16 (linear).
// ---------------------------------------------------------------------------
__device__ __forceinline__ void gl16(const f16* g, f16* l)
{
    __builtin_amdgcn_global_load_lds(
        (const __attribute__((address_space(1))) unsigned int*)g,
        (__attribute__((address_space(3))) unsigned int*)l,
        16, 0, 0);
}

// ---------------------------------------------------------------------------
// LDS chunk swizzle (R6, verified 0 conflicts): logical chunk q of row r is
// stored at physical chunk q ^ ((r>>1)&3). Reads XOR (l16>>1)&3; gl16
// pre-swizzles the GLOBAL source chunk with (lane>>3)&3 (staged row=lane>>2).
// ---------------------------------------------------------------------------

// ---------------------------------------------------------------------------
// 256x256 TN MFMA GEMM, 8-phase schedule + batch->XCD pinning + 0-conflict
// swizzle (R6/R8 state, best verified 255.7us total). 512 threads, 8 waves
// (2M x 4N, per-wave 128x64). BK=64, ring-2 x 2 K-half LDS (128 KB). Counted
// vmcnt(8), raw barriers, setprio MFMA. gx = N-tiles per row.
// MODE: 0 = f16 store; 1 = f16 relu(+bias[col]).
// ---------------------------------------------------------------------------
template<int MODE>
__global__ __launch_bounds__(512, 2) void gemm256(
    const f16* __restrict__ A, size_t sA, int lda,
    const f16* __restrict__ B, size_t sB, int ldb,
    void* __restrict__ Cp, size_t sC, int ldc,
    const float* __restrict__ bias,
    int gx, int K)
{
    __shared__ __align__(16) f16 As[2][2][256 * 32];   // 64 KB
    __shared__ __align__(16) f16 Bs[2][2][256 * 32];   // 64 KB

    const int f = blockIdx.x;
    const int bz = f & 7;
    const int flat = f >> 3;
    const int jsc = gx >> 2;
    const int sh = (jsc <= 1) ? 0 : (31 - __builtin_clz(jsc));
    const int s = flat >> 4, rem = flat & 15;
    const int i0 = ((s >> sh) * 4 + (rem >> 2)) * 256;
    const int j0 = (((jsc <= 1) ? 0 : (s & (jsc - 1))) * 4 + (rem & 3)) * 256;

    A += (size_t)bz * sA;
    B += (size_t)bz * sB;

    const int tid  = threadIdx.x;
    const int lane = tid & 63;
    const int wave = tid >> 6;
    const int wy = wave >> 2;
    const int wx = wave & 3;
    const int quad = lane >> 4, l16 = lane & 15;

    const int srow = wave * 32 + (lane >> 2);
    const int sch  = (lane & 3) ^ ((lane >> 3) & 3);
    const f16* gA0 = A + (size_t)(i0 + srow) * lda + sch * 8;
    const f16* gA1 = gA0 + (size_t)16 * lda;
    const f16* gB0 = B + (size_t)(j0 + srow) * ldb + sch * 8;
    const f16* gB1 = gB0 + (size_t)16 * ldb;
    const int wsg = wave * 1024;

    const int xq = (quad ^ ((l16 >> 1) & 3)) << 3;
    const int ra = (wy * 128 + l16) * 32 + xq;
    const int rb = (wx * 64 + l16) * 32 + xq;

    const int nt = K >> 6;

#define STAGE_A(t, q) do {                                                    \
        const int off_ = (t) * 64 + (q) * 32;                                 \
        gl16(gA0 + off_, &As[(t) & 1][q][wsg]);                               \
        gl16(gA1 + off_, &As[(t) & 1][q][wsg + 512]);                         \
    } while (0)
#define STAGE_B(t, q) do {                                                    \
        const int off_ = (t) * 64 + (q) * 32;                                 \
        gl16(gB0 + off_, &Bs[(t) & 1][q][wsg]);                               \
        gl16(gB1 + off_, &Bs[(t) & 1][q][wsg + 512]);                         \
    } while (0)
#define PH_MFMA(B0) do {                                                      \
        __builtin_amdgcn_s_setprio(1);                                        \
        _Pragma("unroll")                                                     \
        for (int mi = 0; mi < 4; ++mi) {                                      \
            _Pragma("unroll")                                                 \
            for (int ni = 0; ni < 4; ++ni)                                    \
                acc[(B0) + mi][ni] = __builtin_amdgcn_mfma_f32_16x16x32_f16(  \
                    af[mi], bf[ni], acc[(B0) + mi][ni], 0, 0, 0);             \
        }                                                                     \
        __builtin_amdgcn_s_setprio(0);                                        \
    } while (0)

    STAGE_A(0, 0); STAGE_B(0, 0);
    STAGE_A(0, 1); STAGE_B(0, 1);
    STAGE_A(1, 0); STAGE_B(1, 0);

    floatx4 acc[8][4] = {};

    for (int t = 0; t < nt; ++t) {
        const f16* sa0 = &As[t & 1][0][0];
        const f16* sb0 = &Bs[t & 1][0][0];
        const f16* sa1 = &As[t & 1][1][0];
        const f16* sb1 = &Bs[t & 1][1][0];
        half8 af[4], bf[4];

        if (t + 1 < nt) asm volatile("s_waitcnt vmcnt(8)\ns_barrier" ::: "memory");
        else            asm volatile("s_waitcnt vmcnt(4)\ns_barrier" ::: "memory");
        #pragma unroll
        for (int ni = 0; ni < 4; ++ni) bf[ni] = *(const half8*)&sb0[rb + ni * 512];
        #pragma unroll
        for (int mi = 0; mi < 4; ++mi) af[mi] = *(const half8*)&sa0[ra + mi * 512];
        if (t + 1 < nt) STAGE_A(t + 1, 1);
        PH_MFMA(0);

        #pragma unroll
        for (int mi = 0; mi < 4; ++mi) af[mi] = *(const half8*)&sa0[ra + 2048 + mi * 512];
        if (t + 1 < nt) STAGE_B(t + 1, 1);
        PH_MFMA(4);

        if (t + 1 < nt) asm volatile("s_waitcnt vmcnt(8)\ns_barrier" ::: "memory");
        else            asm volatile("s_waitcnt vmcnt(0)\ns_barrier" ::: "memory");
        #pragma unroll
        for (int ni = 0; ni < 4; ++ni) bf[ni] = *(const half8*)&sb1[rb + ni * 512];
        #pragma unroll
        for (int mi = 0; mi < 4; ++mi) af[mi] = *(const half8*)&sa1[ra + mi * 512];
        if (t + 2 < nt) STAGE_A(t + 2, 0);
        PH_MFMA(0);

        #pragma unroll
        for (int mi = 0; mi < 4; ++mi) af[mi] = *(const half8*)&sa1[ra + 2048 + mi * 512];
        if (t + 2 < nt) STAGE_B(t + 2, 0);
        PH_MFMA(4);
    }
#undef STAGE_A
#undef STAGE_B
#undef PH_MFMA

    #pragma unroll
    for (int m = 0; m < 8; ++m) {
        #pragma unroll
        for (int ni = 0; ni < 4; ++ni) {
            const int col = j0 + wx * 64 + ni * 16 + l16;
            #pragma unroll
            for (int r = 0; r < 4; ++r) {
                const int row = i0 + wy * 128 + m * 16 + quad * 4 + r;
                float v = acc[m][ni][r];
                if (MODE == 1) { v += bias[col]; v = v > 0.f ? v : 0.f; }
                ((f16*)Cp)[(size_t)bz * sC + (size_t)row * ldc + col] = (f16)v;
            }
        }
    }
}

// ---------------------------------------------------------------------------
// 128(M)x256(N) TN MFMA GEMM, 8-phase schedule + batch->XCD pinning +
// 0-conflict swizzle (R6/R8 state). 512 threads, 8 waves (2M x 4N), per-wave
// 64x64. BK=64, LDS 96 KB. gxn = N-tiles per row.
// MODE: 0 = f16 store; 2 = f16 relu(+bias[row]); 3 = fp32 relu(+bias[row])+resid.
// ---------------------------------------------------------------------------
template<int MODE>
__global__ __launch_bounds__(512, 2) void gemm_wide(
    const f16* __restrict__ A, size_t sA, int lda,
    const f16* __restrict__ B, size_t sB, int ldb,
    void* __restrict__ Cp, size_t sC, int ldc,
    const float* __restrict__ bias,
    const float* __restrict__ resid, size_t sR,
    int gxn, int K)
{
    __shared__ __align__(16) f16 As[2][2][128 * 32];   // 32 KB
    __shared__ __align__(16) f16 Bs[2][2][256 * 32];   // 64 KB

    const int f = blockIdx.x;
    const int bz = f & 7;
    const int inner = f >> 3;
    const int j0 = (inner % gxn) * 256;
    const int i0 = (inner / gxn) * 128;
    A += (size_t)bz * sA;
    B += (size_t)bz * sB;

    const int tid  = threadIdx.x;
    const int lane = tid & 63;
    const int wave = tid >> 6;
    const int wy = wave >> 2;
    const int wx = wave & 3;
    const int quad = lane >> 4, l16 = lane & 15;

    const int sch = (lane & 3) ^ ((lane >> 3) & 3);
    const f16* gA0 = A + (size_t)(i0 + wave * 16 + (lane >> 2)) * lda + sch * 8;
    const f16* gB0 = B + (size_t)(j0 + wave * 32 + (lane >> 2)) * ldb + sch * 8;
    const f16* gB1 = gB0 + (size_t)16 * ldb;

    const int xq = (quad ^ ((l16 >> 1) & 3)) << 3;
    const int ra = (wy * 64 + l16) * 32 + xq;
    const int rb = (wx * 64 + l16) * 32 + xq;

    const int nt = K >> 6;

#define WSTAGE_A(t, q) do {                                                   \
        gl16(gA0 + (t) * 64 + (q) * 32, &As[(t) & 1][q][wave * 512]);         \
    } while (0)
#define WSTAGE_B(t, q) do {                                                   \
        const int off_ = (t) * 64 + (q) * 32;                                 \
        gl16(gB0 + off_, &Bs[(t) & 1][q][wave * 1024]);                       \
        gl16(gB1 + off_, &Bs[(t) & 1][q][wave * 1024 + 512]);                 \
    } while (0)
#define WPH_MFMA() do {                                                       \
        __builtin_amdgcn_s_setprio(1);                                        \
        _Pragma("unroll")                                                     \
        for (int mi = 0; mi < 4; ++mi) {                                      \
            _Pragma("unroll")                                                 \
            for (int ni = 0; ni < 4; ++ni)                                    \
                acc[mi][ni] = __builtin_amdgcn_mfma_f32_16x16x32_f16(         \
                    af[mi], bf[ni], acc[mi][ni], 0, 0, 0);                    \
        }                                                                     \
        __builtin_amdgcn_s_setprio(0);                                        \
    } while (0)

    WSTAGE_A(0, 0); WSTAGE_B(0, 0);
    WSTAGE_A(0, 1); WSTAGE_B(0, 1);
    WSTAGE_A(1, 0); WSTAGE_B(1, 0);

    floatx4 acc[4][4] = {};

    for (int t = 0; t < nt; ++t) {
        const f16* sa0 = &As[t & 1][0][0];
        const f16* sb0 = &Bs[t & 1][0][0];
        const f16* sa1 = &As[t & 1][1][0];
        const f16* sb1 = &Bs[t & 1][1][0];
        half8 af[4], bf[4];

        if (t + 1 < nt) asm volatile("s_waitcnt vmcnt(6)\ns_barrier" ::: "memory");
        else            asm volatile("s_waitcnt vmcnt(3)\ns_barrier" ::: "memory");
        #pragma unroll
        for (int ni = 0; ni < 4; ++ni) bf[ni] = *(const half8*)&sb0[rb + ni * 512];
        #pragma unroll
        for (int mi = 0; mi < 4; ++mi) af[mi] = *(const half8*)&sa0[ra + mi * 512];
        if (t + 1 < nt) { WSTAGE_A(t + 1, 1); WSTAGE_B(t + 1, 1); }
        WPH_MFMA();

        if (t + 1 < nt) asm volatile("s_waitcnt vmcnt(6)\ns_barrier" ::: "memory");
        else            asm volatile("s_waitcnt vmcnt(0)\ns_barrier" ::: "memory");
        #pragma unroll
        for (int ni = 0; ni < 4; ++ni) bf[ni] = *(const half8*)&sb1[rb + ni * 512];
        #pragma unroll
        for (int mi = 0; mi < 4; ++mi) af[mi] = *(const half8*)&sa1[ra + mi * 512];
        if (t + 2 < nt) { WSTAGE_A(t + 2, 0); WSTAGE_B(t + 2, 0); }
        WPH_MFMA();
    }
#undef WSTAGE_A
#undef WSTAGE_B
#undef WPH_MFMA

    #pragma unroll
    for (int mi = 0; mi < 4; ++mi) {
        #pragma unroll
        for (int ni = 0; ni < 4; ++ni) {
            const int col = j0 + wx * 64 + ni * 16 + l16;
            #pragma unroll
            for (int r = 0; r < 4; ++r) {
                const int row = i0 + wy * 64 + mi * 16 + quad * 4 + r;
                float v = acc[mi][ni][r];
                if (MODE == 2) { v += bias[row]; v = v > 0.f ? v : 0.f; }
                if (MODE == 3) {
                    v += bias[row];
                    v = v > 0.f ? v : 0.f;
                    v += resid[(size_t)bz * sR + (size_t)row * ldc + col];
                    ((float*)Cp)[(size_t)bz * sC + (size_t)row * ldc + col] = v;
                } else {
                    ((f16*)Cp)[(size_t)bz * sC + (size_t)row * ldc + col] = (f16)v;
                }
            }
        }
    }
}

// ---------------------------------------------------------------------------
// in-place fp16 softmax over rows of 2048 (fp32 math). One wave per row,
// 4 rows/block, butterfly shfl_xor reductions — no barriers, no LDS.
// ---------------------------------------------------------------------------
__global__ __launch_bounds__(256) void softmax_f16_kernel(f16* __restrict__ S)
{
    const int lane = threadIdx.x & 63;
    f16* p = S + (size_t)(blockIdx.x * 4 + (threadIdx.x >> 6)) * T_DIM;

    half8 h[4];
    float v[32];
    float m = -1e30f;
    #pragma unroll
    for (int u = 0; u < 4; ++u) {
        h[u] = *((const half8*)p + (u * 64 + lane));
        #pragma unroll
        for (int c = 0; c < 8; ++c) {
            v[u * 8 + c] = (float)h[u][c];
            m = fmaxf(m, v[u * 8 + c]);
        }
    }
    #pragma unroll
    for (int off = 32; off; off >>= 1) m = fmaxf(m, __shfl_xor(m, off));

    float s = 0.f;
    #pragma unroll
    for (int i = 0; i < 32; ++i) { v[i] = __expf(v[i] - m); s += v[i]; }
    #pragma unroll
    for (int off = 32; off; off >>= 1) s += __shfl_xor(s, off);
    const float inv = 1.f / s;

    #pragma unroll
    for (int u = 0; u < 4; ++u) {
        #pragma unroll
        for (int c = 0; c < 8; ++c) h[u][c] = (f16)(v[u * 8 + c] * inv);
        *((half8*)p + (u * 64 + lane)) = h[u];
    }
}

// ---------------------------------------------------------------------------
extern "C" void kernel_launch(void* const* d_in, const int* in_sizes, int n_in,
                              void* d_out, int out_size, void* d_ws, size_t ws_size,
                              hipStream_t stream)
{
    const float* x       = (const float*)d_in[0];
    const float* w_theta = (const float*)d_in[1];
    const float* b_theta = (const float*)d_in[2];
    const float* w_phi   = (const float*)d_in[3];
    const float* b_phi   = (const float*)d_in[4];
    const float* w_g     = (const float*)d_in[5];
    const float* b_g     = (const float*)d_in[6];
    const float* w_w     = (const float*)d_in[7];
    const float* b_w     = (const float*)d_in[8];
    float* out = (float*)d_out;

    const size_t FE = (size_t)B_DIM * C_DIM * T_DIM;   // 8.4M
    const size_t TC = (size_t)T_DIM * C_DIM;
    const size_t TT = (size_t)T_DIM * T_DIM;

    f16* xt      = (f16*)d_ws;
    f16* wtp     = xt + FE;              // merged theta|phi weights [1024][512]
    f16* wg_h    = wtp + 524288;
    f16* ww_h    = wg_h + 262144;
    float* btp   = (float*)(ww_h + 262144);   // merged bias [1024] fp32
    f16* tp      = (f16*)(btp + 1024);   // theta|phi acts [B][T][1024]
    f16* g       = tp + (size_t)B_DIM * T_DIM * 1024;
    f16* scores  = g + FE;               // B*T*T fp16 = 67 MB
    f16* feature = tp;                   // tp dead after scores GEMM

    const dim3 blk(256);
    const dim3 blk512(512);

    // merged prep: weight convert + bias concat + x transpose (one launch)
    prep_kernel<<<dim3(1024 + 4 + 8192), blk, 0, stream>>>(
        x, xt, w_theta, w_phi, w_g, w_w,
        wtp, wtp + 262144, wg_h, ww_h, b_theta, b_phi, btp);

    // merged theta|phi conv: tp[t][0:1024] = relu(xt . wtp + btp)  M=T,N=1024
    gemm256<1><<<dim3(4 * 8 * B_DIM), blk512, 0, stream>>>(
        xt, TC, C_DIM, wtp, 0, C_DIM, tp, (size_t)T_DIM * 1024, 1024,
        btp, 4, C_DIM);
    // g[c][t] = relu(w_g . xt + b_g[c])   M=C=512, N=T
    gemm_wide<2><<<dim3(8 * 4 * B_DIM), blk512, 0, stream>>>(
        wg_h, 0, C_DIM, xt, TC, C_DIM, g, TC, T_DIM, b_g, nullptr, 0,
        8, C_DIM);
    // scores[i][j] = theta . phi; 8x8 inner x 8 batches (4 MB/batch -> L2)
    gemm256<0><<<dim3(8 * 8 * B_DIM), blk512, 0, stream>>>(
        tp, (size_t)T_DIM * 1024, 1024, tp + 512, (size_t)T_DIM * 1024, 1024,
        scores, TT, T_DIM, nullptr, 8, C_DIM);
    softmax_f16_kernel<<<dim3(B_DIM * T_DIM / 4), blk, 0, stream>>>(scores);
    // feature[i][c] = attn . g   M=T, N=C=512, K=T
    gemm_wide<0><<<dim3(2 * 16 * B_DIM), blk512, 0, stream>>>(
        scores, TT, T_DIM, g, TC, T_DIM, feature, TC, C_DIM,
        nullptr, nullptr, 0, 2, T_DIM);
    // out[c][t] = relu(w_w . feature + b_w[c]) + x   M=C=512, N=T
    gemm_wide<3><<<dim3(8 * 4 * B_DIM), blk512, 0, stream>>>(
        ww_h, 0, C_DIM, feature, TC, C_DIM, out, TC, T_DIM, b_w, x, TC,
        8, C_DIM);
}